// Round 4
// baseline (1628.911 us; speedup 1.0000x reference)
//
#include <hip/hip_runtime.h>
#include <hip/hip_bf16.h>

// Problem dims (fixed): T=256, B=8, H=128, IN=256
#define T_LEN 256

typedef _Float16 f16x8 __attribute__((ext_vector_type(8)));
typedef float f32x4 __attribute__((ext_vector_type(4)));

__device__ __forceinline__ float fsig(float x)  { return 1.f/(1.f+__expf(-x)); }
__device__ __forceinline__ float ftanhf(float x){ float e = __expf(2.f*x); return 1.f - 2.f/(e+1.f); }

#define MFMA16(a,b,c) __builtin_amdgcn_mfma_f32_16x16x32_f16(a, b, c, 0, 0, 0)
#define SENT (~0ull)

// ---------------- init: sentinel-fill Hbuf ----------------
// Hbuf: [c=4][t=256][b=8][32 ull] = 262144 ull. Sentinel = all-ones (f16 NaN).
__global__ void k_init(unsigned long long* Hbuf) {
  int n = blockIdx.x*blockDim.x + threadIdx.x;
  if (n < 4*256*8*32) Hbuf[n] = SENT;
}

// ---------------- weight reformat ----------------
// WvPT/WvPbT: [256][128]; gwT: [256][256]; Wih0T: [i=256][o=768]
// Wh: f16 [c=6][o=384][k=128]  (Whh row-major)
// Wx: f16 [cc=4][o=384][k=256] (Wih row-major, cells 2..5)
__global__ void k_prep(const float* __restrict__ WvP, const float* __restrict__ WvPb,
                       const float* __restrict__ gatew,
                       const float* __restrict__ Wih, const float* __restrict__ Whh,
                       float* __restrict__ WvPT, float* __restrict__ WvPbT,
                       float* __restrict__ gwT, float* __restrict__ Wih0T,
                       _Float16* __restrict__ Wx, _Float16* __restrict__ Wh) {
  int n = blockIdx.x*blockDim.x + threadIdx.x;
  int NT = gridDim.x*blockDim.x;
  for (int k = n; k < 256*128; k += NT) {
    int i = k >> 7, h = k & 127;
    WvPT[k]  = WvP[h*256 + i];
    WvPbT[k] = WvPb[h*256 + i];
  }
  for (int k = n; k < 256*256; k += NT) {
    int dd = k >> 8, e = k & 255;
    gwT[k] = gatew[e*256 + dd];
  }
  for (int k = n; k < 256*768; k += NT) {
    int i = k / 768, doo = k % 768;
    Wih0T[k] = Wih[(size_t)doo*256 + i];
  }
  for (int k = n; k < 6*384*128; k += NT) {
    Wh[k] = (_Float16)Whh[k];           // identical flat layout [c][o][128]
  }
  for (int k = n; k < 4*384*256; k += NT) {
    Wx[k] = (_Float16)Wih[(size_t)2*384*256 + k];  // cells 2..5 = Wih rows 2..5
  }
}

// ---------------- prep/pbar projections ----------------
__global__ __launch_bounds__(256) void k_prep_pbar(
    const float* __restrict__ P, const float* __restrict__ WvPT,
    const float* __restrict__ WvPbT, float* __restrict__ prepT,
    float* __restrict__ pbar) {
  __shared__ float Pl[4*256];
  int R0 = blockIdx.x * 4, tid = threadIdx.x;
  for (int k = tid; k < 1024; k += 256) Pl[k] = P[(size_t)R0*256 + k];
  __syncthreads();
  int h = tid & 127;
  const float* Wt = (tid < 128) ? WvPT : WvPbT;
  float acc[4] = {0,0,0,0};
  for (int i = 0; i < 256; ++i) {
    float w = Wt[i*128 + h];
    acc[0] += Pl[i]*w; acc[1] += Pl[256+i]*w;
    acc[2] += Pl[512+i]*w; acc[3] += Pl[768+i]*w;
  }
  #pragma unroll
  for (int r = 0; r < 4; ++r) {
    int R = R0 + r, t = R >> 3, b = R & 7;
    if (tid < 128) prepT[((size_t)b*128 + h)*256 + t] = acc[r];
    else           pbar[(size_t)R*128 + h] = acc[r];
  }
}

// ---------------- fused attention + gate ----------------
__global__ __launch_bounds__(256) void k_attn(
    const float* __restrict__ prepT, const float* __restrict__ pbar,
    const float* __restrict__ vw, const float* __restrict__ gwT,
    float* __restrict__ ug) {
  int b = blockIdx.x & 7, q0 = (blockIdx.x >> 3) * 4;
  int tid = threadIdx.x;
  __shared__ float u[4][256];
  __shared__ float vl[128];
  __shared__ float sc[4][256];
  __shared__ float red[4];
  if (tid < 128) vl[tid] = vw[tid];
  for (int k = tid; k < 512; k += 256) {
    int j = k >> 7, h = k & 127;
    u[j][h] = pbar[(((size_t)(q0+j))*8 + b)*128 + h];
  }
  __syncthreads();
  float s[4] = {0,0,0,0};
  for (int h = 0; h < 128; ++h) {
    float pk = prepT[((size_t)b*128 + h)*256 + tid];
    float vh = vl[h];
    #pragma unroll
    for (int j = 0; j < 4; ++j) {
      float e = __expf(2.f*(u[j][h] + pk));
      s[j] += vh * (1.f - 2.f/(e + 1.f));
    }
  }
  #pragma unroll
  for (int j = 0; j < 4; ++j) {
    float v = s[j];
    #pragma unroll
    for (int off = 32; off > 0; off >>= 1) v = fmaxf(v, __shfl_xor(v, off));
    if ((tid & 63) == 0) red[tid >> 6] = v;
    __syncthreads();
    float m = fmaxf(fmaxf(red[0], red[1]), fmaxf(red[2], red[3]));
    __syncthreads();
    float e = __expf(s[j] - m);
    v = e;
    #pragma unroll
    for (int off = 32; off > 0; off >>= 1) v += __shfl_xor(v, off);
    if ((tid & 63) == 0) red[tid >> 6] = v;
    __syncthreads();
    float sum = red[0] + red[1] + red[2] + red[3];
    __syncthreads();
    sc[j][tid] = e / sum;
  }
  __syncthreads();
  {
    int h = tid & 127, jj = tid >> 7;
    float c0 = 0.f, c1 = 0.f;
    for (int k = 0; k < 256; ++k) {
      float p = pbar[((size_t)k*8 + b)*128 + h];
      c0 += sc[jj][k]   * p;
      c1 += sc[jj+2][k] * p;
    }
    u[jj][128+h]   = c0;
    u[jj+2][128+h] = c1;
  }
  __syncthreads();
  {
    float gg[4] = {0,0,0,0};
    for (int dd = 0; dd < 256; ++dd) {
      float w = gwT[(size_t)dd*256 + tid];
      #pragma unroll
      for (int j = 0; j < 4; ++j) gg[j] += u[j][dd] * w;
    }
    #pragma unroll
    for (int j = 0; j < 4; ++j) {
      float ue = u[j][tid];
      ug[(((size_t)(q0+j))*8 + b)*256 + tid] = ue * fsig(gg[j]);
    }
  }
}

// ---------------- gi0 = ug @ Wih0^T + bih : output [t][o=768][b=8] ----------------
__global__ __launch_bounds__(256) void k_gi0(
    const float* __restrict__ ug, const float* __restrict__ Wih0T,
    const float* __restrict__ bih, float* __restrict__ gi0) {
  __shared__ float ul[8][256];
  __shared__ float st[768*8];
  int t = blockIdx.x, tid = threadIdx.x;
  for (int k = tid; k < 2048; k += 256) ul[k >> 8][k & 255] = ug[(size_t)t*2048 + k];
  __syncthreads();
  float acc[3][8];
  #pragma unroll
  for (int a = 0; a < 3; ++a)
    #pragma unroll
    for (int r = 0; r < 8; ++r) acc[a][r] = 0.f;
  for (int i = 0; i < 256; ++i) {
    float w0 = Wih0T[(size_t)i*768 + tid];
    float w1 = Wih0T[(size_t)i*768 + 256 + tid];
    float w2 = Wih0T[(size_t)i*768 + 512 + tid];
    #pragma unroll
    for (int r = 0; r < 8; ++r) {
      float uu = ul[r][i];
      acc[0][r] += uu*w0; acc[1][r] += uu*w1; acc[2][r] += uu*w2;
    }
  }
  float b0 = bih[tid], b1 = bih[256 + tid], b2 = bih[512 + tid];
  #pragma unroll
  for (int a = 0; a < 3; ++a) {
    int o = a*256 + tid;
    float ba = (a == 0) ? b0 : (a == 1) ? b1 : b2;
    #pragma unroll
    for (int r = 0; r < 8; ++r) st[o*8 + r] = acc[a][r] + ba;
  }
  __syncthreads();
  #pragma unroll
  for (int j = 0; j < 6; ++j) {
    int idx = j*256 + tid;
    ((f32x4*)gi0)[(size_t)t*1536 + idx] = ((const f32x4*)st)[idx];
  }
}

// ---------------- persistent GRU v3: sentinel handoff + register x-prefetch ----
// 6 WGs x 512 threads, one cell per WG. Cell c: l=c>>1, d=c&1.
// Own h: LDS double-buffer hlds[2][8][128] f16, byte ^ (b<<4) swizzle.
// x input (l>0): loaded straight into MFMA A-frag registers from Hbuf (agent
// atomics), prefetched 1 step ahead, sentinel-validated at use (0xFFFF = NaN,
// real |h|<=1 never NaN). No flags, no fences: each 8B word self-validates.
// Publish (l<2): post-barrier LDS read -> relaxed 8B atomic stores.
__global__ __launch_bounds__(512, 2) void k_gru3(
    const _Float16* __restrict__ Wx, const _Float16* __restrict__ Wh,
    const float* __restrict__ gi0, const float* __restrict__ bih,
    const float* __restrict__ bhh, unsigned long long* Hbuf,
    float* __restrict__ out)
{
  const int c = blockIdx.x, l = c >> 1, d = c & 1;
  const int tid = threadIdx.x;
  const int w = tid >> 6, lane = tid & 63;
  const int lo = lane & 15, hi = lane >> 4;

  __shared__ _Float16 hlds[2][8*128];   // 4 KiB

  { // zero both h buffers
    f16x8 z = {0,0,0,0,0,0,0,0};
    for (int p = tid; p < 256; p += 512) ((f16x8*)hlds)[p] = z;
  }

  // ---- B-fragments (weights) into registers ----
  f16x8 bh[3][4];
  #pragma unroll
  for (int nt = 0; nt < 3; ++nt) {
    int o = 16 * (w + 8*nt) + lo;
    #pragma unroll
    for (int ks = 0; ks < 4; ++ks)
      bh[nt][ks] = *(const f16x8*)(Wh + ((size_t)c*384 + o)*128 + 32*ks + 8*hi);
  }
  f16x8 bx[3][8];
  if (l > 0) {
    #pragma unroll
    for (int nt = 0; nt < 3; ++nt) {
      int o = 16 * (w + 8*nt) + lo;
      #pragma unroll
      for (int ks = 0; ks < 8; ++ks)
        bx[nt][ks] = *(const f16x8*)(Wx + ((size_t)(c-2)*384 + o)*256 + 32*ks + 8*hi);
    }
  }

  // ---- per-lane biases (h index = 16w + lo; gates r,z,n) ----
  const int hidx = 16*w + lo;
  float b_r, b_z, b_in, b_hn;
  {
    const size_t bb = (size_t)c * 384;
    float bir = bih[bb + hidx], biz = bih[bb + 128 + hidx], bin = bih[bb + 256 + hidx];
    float bhr = bhh[bb + hidx], bhz = bhh[bb + 128 + hidx], bhn = bhh[bb + 256 + hidx];
    if (l == 0) { b_r = bhr; b_z = bhz; b_in = 0.f;  b_hn = bhn; }
    else        { b_r = bir + bhr; b_z = biz + bhz; b_in = bin; b_hn = bhn; }
  }

  // ---- consumer x-address bases (Hbuf ull index) ----
  // chunk ks(0..7): cell = ks<4 ? cinf : cinf+1 ; ull = cell*65536 + t*256
  //                 + (lo&7)*32 + 8*(ks&3) + 2*hi ; 2 ulls per chunk.
  const int cinf = (l - 1) * 2;
  const size_t sb_f = ((size_t)cinf * 65536)     + (size_t)(lo & 7) * 32 + 2*hi;
  const size_t sb_b = ((size_t)(cinf+1) * 65536) + (size_t)(lo & 7) * 32 + 2*hi;

  unsigned long long xu[16];
  f32x4 gx0, gx1, gx2;

  auto issue_x = [&](int t) {
    #pragma unroll
    for (int ks = 0; ks < 4; ++ks) {
      size_t i0 = sb_f + (size_t)t*256 + 8*ks;
      xu[2*ks]     = __hip_atomic_load(Hbuf+i0,   __ATOMIC_RELAXED, __HIP_MEMORY_SCOPE_AGENT);
      xu[2*ks+1]   = __hip_atomic_load(Hbuf+i0+1, __ATOMIC_RELAXED, __HIP_MEMORY_SCOPE_AGENT);
      size_t i1 = sb_b + (size_t)t*256 + 8*ks;
      xu[8+2*ks]   = __hip_atomic_load(Hbuf+i1,   __ATOMIC_RELAXED, __HIP_MEMORY_SCOPE_AGENT);
      xu[8+2*ks+1] = __hip_atomic_load(Hbuf+i1+1, __ATOMIC_RELAXED, __HIP_MEMORY_SCOPE_AGENT);
    }
  };
  auto issue_g = [&](int t) {
    const float* g = gi0 + ((size_t)t*768 + (size_t)d*384) * 8;
    int b0 = 4 * (hi & 1);
    gx0 = *(const f32x4*)(g + (size_t)hidx*8 + b0);
    gx1 = *(const f32x4*)(g + ((size_t)128 + hidx)*8 + b0);
    gx2 = *(const f32x4*)(g + ((size_t)256 + hidx)*8 + b0);
  };

  float hp[4] = {0,0,0,0};
  __syncthreads();

  // prologue prefetch for t=0
  if (l > 0) issue_x(0); else issue_g(0);

  for (int t = 0; t < T_LEN; ++t) {
    // -- A: h-part MFMAs from hlds[t&1] --
    f32x4 ah0 = {0,0,0,0}, ah1 = {0,0,0,0}, ah2 = {0,0,0,0};
    {
      const char* hb = (const char*)hlds[t & 1];
      f16x8 a[4];
      #pragma unroll
      for (int ks = 0; ks < 4; ++ks) {
        int byte = ((lo & 7)*256 + (32*ks + 8*hi)*2) ^ ((lo & 7) << 4);
        a[ks] = *(const f16x8*)(hb + byte);
      }
      #pragma unroll
      for (int ks = 0; ks < 4; ++ks) {
        ah0 = MFMA16(a[ks], bh[0][ks], ah0);
        ah1 = MFMA16(a[ks], bh[1][ks], ah1);
        ah2 = MFMA16(a[ks], bh[2][ks], ah2);
      }
    }
    // -- B: validate prefetched x; C: x-part MFMAs --
    f32x4 ax0, ax1, ax2;
    if (l > 0) {
      while (true) {
        int bad = 0;
        #pragma unroll
        for (int k2 = 0; k2 < 16; ++k2) bad |= (xu[k2] == SENT) ? 1 : 0;
        if (!__any(bad)) break;
        __builtin_amdgcn_s_sleep(1);
        issue_x(t);
      }
      ax0 = (f32x4){0,0,0,0}; ax1 = (f32x4){0,0,0,0}; ax2 = (f32x4){0,0,0,0};
      #pragma unroll
      for (int ks = 0; ks < 8; ++ks) {
        f16x8 a;
        ((unsigned long long*)&a)[0] = xu[2*ks];
        ((unsigned long long*)&a)[1] = xu[2*ks+1];
        ax0 = MFMA16(a, bx[0][ks], ax0);
        ax1 = MFMA16(a, bx[1][ks], ax1);
        ax2 = MFMA16(a, bx[2][ks], ax2);
      }
    } else {
      ax0 = gx0; ax1 = gx1; ax2 = gx2;
    }
    // -- D: prefetch next step's x / gi --
    {
      int tn = (t < T_LEN-1) ? t + 1 : t;
      if (l > 0) issue_x(tn); else issue_g(tn);
    }
    // -- E: combine gates + state update (lanes<32: b = 4*hi+q) --
    float hn[4];
    #pragma unroll
    for (int q = 0; q < 4; ++q) {
      float r  = fsig(ax0[q] + ah0[q] + b_r);
      float z  = fsig(ax1[q] + ah1[q] + b_z);
      float nn = ftanhf(ax2[q] + b_in + r * (ah2[q] + b_hn));
      hn[q] = (1.f - z) * nn + z * hp[q];
      hp[q] = hn[q];
    }
    // -- F: write h(t) into hlds[(t+1)&1] + out (l==2) --
    if (lane < 32) {
      char* hb = (char*)hlds[(t + 1) & 1];
      #pragma unroll
      for (int q = 0; q < 4; ++q) {
        int b = 4*hi + q;
        int byte = (b*256 + hidx*2) ^ (b << 4);
        *(_Float16*)(hb + byte) = (_Float16)hn[q];
        if (l == 2) out[((size_t)b*256 + t)*256 + d*128 + hidx] = hn[q];
      }
    }
    __syncthreads();
    // -- H: publish h(t) (producers l<2): fire-and-forget 8B atomics --
    if (l < 2 && tid < 128) {
      int b = tid >> 4, p = tid & 15;
      int byte = (b*256 + p*16) ^ (b << 4);
      const unsigned long long* src =
          (const unsigned long long*)((const char*)hlds[(t + 1) & 1] + byte);
      unsigned long long v0 = src[0], v1 = src[1];
      size_t idx = ((size_t)c*65536) + (size_t)t*256 + (size_t)b*32 + 2*p;
      __hip_atomic_store(Hbuf+idx,   v0, __ATOMIC_RELAXED, __HIP_MEMORY_SCOPE_AGENT);
      __hip_atomic_store(Hbuf+idx+1, v1, __ATOMIC_RELAXED, __HIP_MEMORY_SCOPE_AGENT);
    }
  }
}

extern "C" void kernel_launch(void* const* d_in, const int* in_sizes, int n_in,
                              void* d_out, int out_size, void* d_ws, size_t ws_size,
                              hipStream_t stream) {
  (void)in_sizes; (void)n_in; (void)out_size; (void)ws_size;
  const float* P     = (const float*)d_in[0];
  const float* vw    = (const float*)d_in[2];
  const float* WvP   = (const float*)d_in[3];
  const float* WvPb  = (const float*)d_in[4];
  const float* gatew = (const float*)d_in[5];
  const float* Wih   = (const float*)d_in[6];
  const float* Whh   = (const float*)d_in[7];
  const float* bih   = (const float*)d_in[8];
  const float* bhh   = (const float*)d_in[9];
  float* out = (float*)d_out;

  char* wsp = (char*)d_ws;
  size_t off = 0;
  auto alloc = [&](size_t nbytes) -> void* {
    void* p = wsp + off;
    off += (nbytes + 255) & ~(size_t)255;
    return p;
  };
  float*    prepT = (float*)   alloc((size_t)8*128*256*4);
  float*    pbar  = (float*)   alloc((size_t)256*8*128*4);
  float*    ug    = (float*)   alloc((size_t)256*8*256*4);
  float*    gi0   = (float*)   alloc((size_t)256*768*8*4);     // [t][o][b]
  unsigned long long* Hbuf = (unsigned long long*)alloc((size_t)4*256*8*32*8);
  _Float16* Wx    = (_Float16*)alloc((size_t)4*384*256*2);
  _Float16* Wh    = (_Float16*)alloc((size_t)6*384*128*2);
  float*    WvPT  = (float*)   alloc((size_t)256*128*4);
  float*    WvPbT = (float*)   alloc((size_t)256*128*4);
  float*    gwT   = (float*)   alloc((size_t)256*256*4);
  float*    Wih0T = (float*)   alloc((size_t)256*768*4);

  hipLaunchKernelGGL(k_init, dim3(1024), dim3(256), 0, stream, Hbuf);
  hipLaunchKernelGGL(k_prep, dim3(256), dim3(256), 0, stream,
                     WvP, WvPb, gatew, Wih, Whh, WvPT, WvPbT, gwT, Wih0T, Wx, Wh);
  hipLaunchKernelGGL(k_prep_pbar, dim3(512), dim3(256), 0, stream,
                     P, WvPT, WvPbT, prepT, pbar);
  hipLaunchKernelGGL(k_attn, dim3(512), dim3(256), 0, stream,
                     prepT, pbar, vw, gwT, ug);
  hipLaunchKernelGGL(k_gi0, dim3(256), dim3(256), 0, stream,
                     ug, Wih0T, bih, gi0);
  hipLaunchKernelGGL(k_gru3, dim3(6), dim3(512), 0, stream,
                     Wx, Wh, gi0, bih, bhh, Hbuf, out);
}

// Round 5
// 654.048 us; speedup vs baseline: 2.4905x; 2.4905x over previous
//
#include <hip/hip_runtime.h>
#include <hip/hip_bf16.h>

// Problem dims (fixed): T=256, B=8, H=128, IN=256
#define T_LEN 256
#define CHUNK 8
#define NCHUNK (T_LEN / CHUNK)

typedef _Float16 f16x8 __attribute__((ext_vector_type(8)));
typedef float f32x4 __attribute__((ext_vector_type(4)));

__device__ __forceinline__ float fsig(float x)  { return 1.f/(1.f+__expf(-x)); }
__device__ __forceinline__ float ftanhf(float x){ float e = __expf(2.f*x); return 1.f - 2.f/(e+1.f); }

#define MFMA16(a,b,c) __builtin_amdgcn_mfma_f32_16x16x32_f16(a, b, c, 0, 0, 0)

// ---------------- init: zero chunk flags ----------------
__global__ void k_init(unsigned* flags) {
  int n = threadIdx.x;
  if (n < 64) flags[n] = 0u;
}

// ---------------- weight reformat ----------------
// WvPT/WvPbT: [256][128]; gwT: [256][256]; Wih0T: [i=256][o=768]
// Wh: f16 [c=6][o=384][k=128]  (Whh row-major)
// Wx: f16 [cc=4][o=384][k=256] (Wih row-major, cells 2..5)
__global__ void k_prep(const float* __restrict__ WvP, const float* __restrict__ WvPb,
                       const float* __restrict__ gatew,
                       const float* __restrict__ Wih, const float* __restrict__ Whh,
                       float* __restrict__ WvPT, float* __restrict__ WvPbT,
                       float* __restrict__ gwT, float* __restrict__ Wih0T,
                       _Float16* __restrict__ Wx, _Float16* __restrict__ Wh) {
  int n = blockIdx.x*blockDim.x + threadIdx.x;
  int NT = gridDim.x*blockDim.x;
  for (int k = n; k < 256*128; k += NT) {
    int i = k >> 7, h = k & 127;
    WvPT[k]  = WvP[h*256 + i];
    WvPbT[k] = WvPb[h*256 + i];
  }
  for (int k = n; k < 256*256; k += NT) {
    int dd = k >> 8, e = k & 255;
    gwT[k] = gatew[e*256 + dd];
  }
  for (int k = n; k < 256*768; k += NT) {
    int i = k / 768, doo = k % 768;
    Wih0T[k] = Wih[(size_t)doo*256 + i];
  }
  for (int k = n; k < 6*384*128; k += NT) {
    Wh[k] = (_Float16)Whh[k];           // identical flat layout [c][o][128]
  }
  for (int k = n; k < 4*384*256; k += NT) {
    Wx[k] = (_Float16)Wih[(size_t)2*384*256 + k];  // cells 2..5 = Wih rows 2..5
  }
}

// ---------------- prep/pbar projections ----------------
__global__ __launch_bounds__(256) void k_prep_pbar(
    const float* __restrict__ P, const float* __restrict__ WvPT,
    const float* __restrict__ WvPbT, float* __restrict__ prepT,
    float* __restrict__ pbar) {
  __shared__ float Pl[4*256];
  int R0 = blockIdx.x * 4, tid = threadIdx.x;
  for (int k = tid; k < 1024; k += 256) Pl[k] = P[(size_t)R0*256 + k];
  __syncthreads();
  int h = tid & 127;
  const float* Wt = (tid < 128) ? WvPT : WvPbT;
  float acc[4] = {0,0,0,0};
  for (int i = 0; i < 256; ++i) {
    float w = Wt[i*128 + h];
    acc[0] += Pl[i]*w; acc[1] += Pl[256+i]*w;
    acc[2] += Pl[512+i]*w; acc[3] += Pl[768+i]*w;
  }
  #pragma unroll
  for (int r = 0; r < 4; ++r) {
    int R = R0 + r, t = R >> 3, b = R & 7;
    if (tid < 128) prepT[((size_t)b*128 + h)*256 + t] = acc[r];
    else           pbar[(size_t)R*128 + h] = acc[r];
  }
}

// ---------------- fused attention + gate ----------------
__global__ __launch_bounds__(256) void k_attn(
    const float* __restrict__ prepT, const float* __restrict__ pbar,
    const float* __restrict__ vw, const float* __restrict__ gwT,
    float* __restrict__ ug) {
  int b = blockIdx.x & 7, q0 = (blockIdx.x >> 3) * 4;
  int tid = threadIdx.x;
  __shared__ float u[4][256];
  __shared__ float vl[128];
  __shared__ float sc[4][256];
  __shared__ float red[4];
  if (tid < 128) vl[tid] = vw[tid];
  for (int k = tid; k < 512; k += 256) {
    int j = k >> 7, h = k & 127;
    u[j][h] = pbar[(((size_t)(q0+j))*8 + b)*128 + h];
  }
  __syncthreads();
  float s[4] = {0,0,0,0};
  for (int h = 0; h < 128; ++h) {
    float pk = prepT[((size_t)b*128 + h)*256 + tid];
    float vh = vl[h];
    #pragma unroll
    for (int j = 0; j < 4; ++j) {
      float e = __expf(2.f*(u[j][h] + pk));
      s[j] += vh * (1.f - 2.f/(e + 1.f));
    }
  }
  #pragma unroll
  for (int j = 0; j < 4; ++j) {
    float v = s[j];
    #pragma unroll
    for (int off = 32; off > 0; off >>= 1) v = fmaxf(v, __shfl_xor(v, off));
    if ((tid & 63) == 0) red[tid >> 6] = v;
    __syncthreads();
    float m = fmaxf(fmaxf(red[0], red[1]), fmaxf(red[2], red[3]));
    __syncthreads();
    float e = __expf(s[j] - m);
    v = e;
    #pragma unroll
    for (int off = 32; off > 0; off >>= 1) v += __shfl_xor(v, off);
    if ((tid & 63) == 0) red[tid >> 6] = v;
    __syncthreads();
    float sum = red[0] + red[1] + red[2] + red[3];
    __syncthreads();
    sc[j][tid] = e / sum;
  }
  __syncthreads();
  {
    int h = tid & 127, jj = tid >> 7;
    float c0 = 0.f, c1 = 0.f;
    for (int k = 0; k < 256; ++k) {
      float p = pbar[((size_t)k*8 + b)*128 + h];
      c0 += sc[jj][k]   * p;
      c1 += sc[jj+2][k] * p;
    }
    u[jj][128+h]   = c0;
    u[jj+2][128+h] = c1;
  }
  __syncthreads();
  {
    float gg[4] = {0,0,0,0};
    for (int dd = 0; dd < 256; ++dd) {
      float w = gwT[(size_t)dd*256 + tid];
      #pragma unroll
      for (int j = 0; j < 4; ++j) gg[j] += u[j][dd] * w;
    }
    #pragma unroll
    for (int j = 0; j < 4; ++j) {
      float ue = u[j][tid];
      ug[(((size_t)(q0+j))*8 + b)*256 + tid] = ue * fsig(gg[j]);
    }
  }
}

// ---------------- gi0 = ug @ Wih0^T + bih : output [t][o=768][b=8] ----------------
__global__ __launch_bounds__(256) void k_gi0(
    const float* __restrict__ ug, const float* __restrict__ Wih0T,
    const float* __restrict__ bih, float* __restrict__ gi0) {
  __shared__ float ul[8][256];
  __shared__ float st[768*8];
  int t = blockIdx.x, tid = threadIdx.x;
  for (int k = tid; k < 2048; k += 256) ul[k >> 8][k & 255] = ug[(size_t)t*2048 + k];
  __syncthreads();
  float acc[3][8];
  #pragma unroll
  for (int a = 0; a < 3; ++a)
    #pragma unroll
    for (int r = 0; r < 8; ++r) acc[a][r] = 0.f;
  for (int i = 0; i < 256; ++i) {
    float w0 = Wih0T[(size_t)i*768 + tid];
    float w1 = Wih0T[(size_t)i*768 + 256 + tid];
    float w2 = Wih0T[(size_t)i*768 + 512 + tid];
    #pragma unroll
    for (int r = 0; r < 8; ++r) {
      float uu = ul[r][i];
      acc[0][r] += uu*w0; acc[1][r] += uu*w1; acc[2][r] += uu*w2;
    }
  }
  float b0 = bih[tid], b1 = bih[256 + tid], b2 = bih[512 + tid];
  #pragma unroll
  for (int a = 0; a < 3; ++a) {
    int o = a*256 + tid;
    float ba = (a == 0) ? b0 : (a == 1) ? b1 : b2;
    #pragma unroll
    for (int r = 0; r < 8; ++r) st[o*8 + r] = acc[a][r] + ba;
  }
  __syncthreads();
  #pragma unroll
  for (int j = 0; j < 6; ++j) {
    int idx = j*256 + tid;
    ((f32x4*)gi0)[(size_t)t*1536 + idx] = ((const f32x4*)st)[idx];
  }
}

// ---------------- persistent GRU v4: CHUNKED pipeline handoff ----------------
// 6 WGs x 512 threads, one cell per WG. Cell c: l=c>>1, d=c&1.
// Handoff granularity = CHUNK(8) steps: one flag poll + one 32KB LDS x-chunk
// load per 8 steps. Producer publishes h per step (fire-and-forget agent
// atomics), raises chunk flag after vmcnt drain. Layer 0 has no input dep and
// runs ahead, so steady-state polls succeed immediately.
// Hbuf: [c=4][t=256][b=8][32 ull]. flags[c]: monotonic chunk counter.
__global__ __launch_bounds__(512, 2) void k_gru4(
    const _Float16* __restrict__ Wx, const _Float16* __restrict__ Wh,
    const float* __restrict__ gi0, const float* __restrict__ bih,
    const float* __restrict__ bhh, unsigned long long* Hbuf,
    float* __restrict__ out, unsigned* flags)
{
  const int c = blockIdx.x, l = c >> 1, d = c & 1;
  const int tid = threadIdx.x;
  const int w = tid >> 6, lane = tid & 63;
  const int lo = lane & 15, hi = lane >> 4;

  __shared__ _Float16 XL[CHUNK * 8 * 256];   // 32 KiB: [tt][b(512B row)][256 f16], swizzled
  __shared__ _Float16 hlds[2][8*128];        // 4 KiB double-buffered own h

  { // zero both h buffers
    f16x8 z = {0,0,0,0,0,0,0,0};
    for (int p = tid; p < 256; p += 512) ((f16x8*)hlds)[p] = z;
  }

  // ---- B-fragments (weights) into registers ----
  f16x8 bh[3][4];
  #pragma unroll
  for (int nt = 0; nt < 3; ++nt) {
    int o = 16 * (w + 8*nt) + lo;
    #pragma unroll
    for (int ks = 0; ks < 4; ++ks)
      bh[nt][ks] = *(const f16x8*)(Wh + ((size_t)c*384 + o)*128 + 32*ks + 8*hi);
  }
  f16x8 bx[3][8];
  if (l > 0) {
    #pragma unroll
    for (int nt = 0; nt < 3; ++nt) {
      int o = 16 * (w + 8*nt) + lo;
      #pragma unroll
      for (int ks = 0; ks < 8; ++ks)
        bx[nt][ks] = *(const f16x8*)(Wx + ((size_t)(c-2)*384 + o)*256 + 32*ks + 8*hi);
    }
  }

  // ---- per-lane biases (h index = 16w + lo; gates r,z,n) ----
  const int hidx = 16*w + lo;
  float b_r, b_z, b_in, b_hn;
  {
    const size_t bb = (size_t)c * 384;
    float bir = bih[bb + hidx], biz = bih[bb + 128 + hidx], bin = bih[bb + 256 + hidx];
    float bhr = bhh[bb + hidx], bhz = bhh[bb + 128 + hidx], bhn = bhh[bb + 256 + hidx];
    if (l == 0) { b_r = bhr; b_z = bhz; b_in = 0.f;  b_hn = bhn; }
    else        { b_r = bir + bhr; b_z = biz + bhz; b_in = bin; b_hn = bhn; }
  }

  const int cinf = (l - 1) * 2;

  f32x4 gx0, gx1, gx2;
  auto issue_g = [&](int t) {
    const float* g = gi0 + ((size_t)t*768 + (size_t)d*384) * 8;
    int b0 = 4 * (hi & 1);
    gx0 = *(const f32x4*)(g + (size_t)hidx*8 + b0);
    gx1 = *(const f32x4*)(g + ((size_t)128 + hidx)*8 + b0);
    gx2 = *(const f32x4*)(g + ((size_t)256 + hidx)*8 + b0);
  };

  float hp[4] = {0,0,0,0};
  if (l == 0) issue_g(0);
  __syncthreads();

  for (int tc = 0; tc < NCHUNK; ++tc) {
    // ---- chunk handoff: poll both producer flags, bulk-load x chunk ----
    if (l > 0) {
      if (tid == 0) {
        while (__hip_atomic_load(flags + cinf, __ATOMIC_RELAXED,
                                 __HIP_MEMORY_SCOPE_AGENT) <= (unsigned)tc)
          __builtin_amdgcn_s_sleep(8);
        while (__hip_atomic_load(flags + cinf + 1, __ATOMIC_RELAXED,
                                 __HIP_MEMORY_SCOPE_AGENT) <= (unsigned)tc)
          __builtin_amdgcn_s_sleep(8);
        __builtin_amdgcn_fence(__ATOMIC_ACQUIRE, "agent");
      }
      __syncthreads();   // also closes WAR on XL from previous chunk
      #pragma unroll
      for (int r = 0; r < 8; ++r) {
        int u = r*512 + tid;                  // 4096 8B units
        int cell = u >> 11, rem = u & 2047;
        int tt = rem >> 8, b = (rem >> 5) & 7, p = rem & 31;
        unsigned long long v = __hip_atomic_load(
            Hbuf + (((size_t)(cinf + cell)) << 16)
                 + (size_t)(tc*CHUNK + tt)*256 + b*32 + p,
            __ATOMIC_RELAXED, __HIP_MEMORY_SCOPE_AGENT);
        int byte = (tt*4096 + b*512 + cell*256 + p*8) ^ ((b & 7) << 4);
        *(unsigned long long*)((char*)XL + byte) = v;
      }
      __syncthreads();
    }

    // ---- 8 steps from LDS/registers ----
    for (int tt = 0; tt < CHUNK; ++tt) {
      const int t = tc*CHUNK + tt;
      // h-part MFMAs from hlds[t&1]
      f32x4 ah0 = {0,0,0,0}, ah1 = {0,0,0,0}, ah2 = {0,0,0,0};
      {
        const char* hb = (const char*)hlds[t & 1];
        f16x8 a[4];
        #pragma unroll
        for (int ks = 0; ks < 4; ++ks) {
          int byte = ((lo & 7)*256 + (32*ks + 8*hi)*2) ^ ((lo & 7) << 4);
          a[ks] = *(const f16x8*)(hb + byte);
        }
        #pragma unroll
        for (int ks = 0; ks < 4; ++ks) {
          ah0 = MFMA16(a[ks], bh[0][ks], ah0);
          ah1 = MFMA16(a[ks], bh[1][ks], ah1);
          ah2 = MFMA16(a[ks], bh[2][ks], ah2);
        }
      }
      // x-part
      f32x4 ax0, ax1, ax2;
      if (l > 0) {
        ax0 = (f32x4){0,0,0,0}; ax1 = (f32x4){0,0,0,0}; ax2 = (f32x4){0,0,0,0};
        f16x8 a[8];
        #pragma unroll
        for (int ks = 0; ks < 8; ++ks) {
          int byte = (tt*4096 + (lo & 7)*512 + 64*ks + 16*hi) ^ ((lo & 7) << 4);
          a[ks] = *(const f16x8*)((const char*)XL + byte);
        }
        #pragma unroll
        for (int ks = 0; ks < 8; ++ks) {
          ax0 = MFMA16(a[ks], bx[0][ks], ax0);
          ax1 = MFMA16(a[ks], bx[1][ks], ax1);
          ax2 = MFMA16(a[ks], bx[2][ks], ax2);
        }
      } else {
        ax0 = gx0; ax1 = gx1; ax2 = gx2;
        if (t < T_LEN - 1) issue_g(t + 1);
      }
      // combine gates + state update (lanes<32: b = 4*hi+q)
      float hn[4];
      #pragma unroll
      for (int q = 0; q < 4; ++q) {
        float r  = fsig(ax0[q] + ah0[q] + b_r);
        float z  = fsig(ax1[q] + ah1[q] + b_z);
        float nn = ftanhf(ax2[q] + b_in + r * (ah2[q] + b_hn));
        hn[q] = (1.f - z) * nn + z * hp[q];
        hp[q] = hn[q];
      }
      // write h(t) into hlds[(t+1)&1] + out (l==2)
      if (lane < 32) {
        char* hb2 = (char*)hlds[(t + 1) & 1];
        #pragma unroll
        for (int q = 0; q < 4; ++q) {
          int b = 4*hi + q;
          int byte = (b*256 + hidx*2) ^ (b << 4);
          *(_Float16*)(hb2 + byte) = (_Float16)hn[q];
          if (l == 2) out[((size_t)b*256 + t)*256 + d*128 + hidx] = hn[q];
        }
      }
      __syncthreads();
      // publish h(t): fire-and-forget agent atomics (producers l<2)
      if (l < 2 && tid < 128) {
        int b = tid >> 4, p = tid & 15;
        int byte = (b*256 + p*16) ^ (b << 4);
        const unsigned long long* src =
            (const unsigned long long*)((const char*)hlds[(t + 1) & 1] + byte);
        unsigned long long v0 = src[0], v1 = src[1];
        size_t idx = (((size_t)c) << 16) + (size_t)t*256 + (size_t)b*32 + 2*p;
        __hip_atomic_store(Hbuf+idx,   v0, __ATOMIC_RELAXED, __HIP_MEMORY_SCOPE_AGENT);
        __hip_atomic_store(Hbuf+idx+1, v1, __ATOMIC_RELAXED, __HIP_MEMORY_SCOPE_AGENT);
      }
    }

    // ---- raise chunk flag (producers) ----
    if (l < 2) {
      asm volatile("s_waitcnt vmcnt(0)" ::: "memory");  // drain this thread's stores
      __syncthreads();                                  // all threads drained
      if (tid == 0)
        __hip_atomic_store(flags + c, (unsigned)(tc + 1),
                           __ATOMIC_RELEASE, __HIP_MEMORY_SCOPE_AGENT);
    }
  }
}

extern "C" void kernel_launch(void* const* d_in, const int* in_sizes, int n_in,
                              void* d_out, int out_size, void* d_ws, size_t ws_size,
                              hipStream_t stream) {
  (void)in_sizes; (void)n_in; (void)out_size; (void)ws_size;
  const float* P     = (const float*)d_in[0];
  const float* vw    = (const float*)d_in[2];
  const float* WvP   = (const float*)d_in[3];
  const float* WvPb  = (const float*)d_in[4];
  const float* gatew = (const float*)d_in[5];
  const float* Wih   = (const float*)d_in[6];
  const float* Whh   = (const float*)d_in[7];
  const float* bih   = (const float*)d_in[8];
  const float* bhh   = (const float*)d_in[9];
  float* out = (float*)d_out;

  char* wsp = (char*)d_ws;
  size_t off = 0;
  auto alloc = [&](size_t nbytes) -> void* {
    void* p = wsp + off;
    off += (nbytes + 255) & ~(size_t)255;
    return p;
  };
  float*    prepT = (float*)   alloc((size_t)8*128*256*4);
  float*    pbar  = (float*)   alloc((size_t)256*8*128*4);
  float*    ug    = (float*)   alloc((size_t)256*8*256*4);
  float*    gi0   = (float*)   alloc((size_t)256*768*8*4);     // [t][o][b]
  unsigned long long* Hbuf = (unsigned long long*)alloc((size_t)4*256*8*32*8);
  _Float16* Wx    = (_Float16*)alloc((size_t)4*384*256*2);
  _Float16* Wh    = (_Float16*)alloc((size_t)6*384*128*2);
  float*    WvPT  = (float*)   alloc((size_t)256*128*4);
  float*    WvPbT = (float*)   alloc((size_t)256*128*4);
  float*    gwT   = (float*)   alloc((size_t)256*256*4);
  float*    Wih0T = (float*)   alloc((size_t)256*768*4);
  unsigned* flags = (unsigned*)alloc((size_t)64*4);

  hipLaunchKernelGGL(k_init, dim3(1), dim3(64), 0, stream, flags);
  hipLaunchKernelGGL(k_prep, dim3(256), dim3(256), 0, stream,
                     WvP, WvPb, gatew, Wih, Whh, WvPT, WvPbT, gwT, Wih0T, Wx, Wh);
  hipLaunchKernelGGL(k_prep_pbar, dim3(512), dim3(256), 0, stream,
                     P, WvPT, WvPbT, prepT, pbar);
  hipLaunchKernelGGL(k_attn, dim3(512), dim3(256), 0, stream,
                     prepT, pbar, vw, gwT, ug);
  hipLaunchKernelGGL(k_gi0, dim3(256), dim3(256), 0, stream,
                     ug, Wih0T, bih, gi0);
  hipLaunchKernelGGL(k_gru4, dim3(6), dim3(512), 0, stream,
                     Wx, Wh, gi0, bih, bhh, Hbuf, out, flags);
}

// Round 6
// 650.242 us; speedup vs baseline: 2.5051x; 1.0059x over previous
//
#include <hip/hip_runtime.h>
#include <hip/hip_bf16.h>

// Problem dims (fixed): T=256, B=8, H=128, IN=256
#define T_LEN 256
#define CHUNK 8
#define NCHUNK (T_LEN / CHUNK)

typedef _Float16 f16x8 __attribute__((ext_vector_type(8)));
typedef float f32x4 __attribute__((ext_vector_type(4)));

__device__ __forceinline__ float fsig(float x)  { return 1.f/(1.f+__expf(-x)); }
__device__ __forceinline__ float ftanhf(float x){ float e = __expf(2.f*x); return 1.f - 2.f/(e+1.f); }

#define MFMA16(a,b,c) __builtin_amdgcn_mfma_f32_16x16x32_f16(a, b, c, 0, 0, 0)

// Opaque register pin: value becomes an asm-defined register tuple the
// compiler cannot rematerialize from memory (prevents weight reloads in-loop).
#define PIN(x) asm volatile("" : "+v"(*reinterpret_cast<f32x4*>(&(x))))

// ---------------- init: zero chunk flags ----------------
__global__ void k_init(unsigned* flags) {
  int n = threadIdx.x;
  if (n < 64) flags[n] = 0u;
}

// ---------------- weight reformat ----------------
// WvPT/WvPbT: [256][128]; gwT: [256][256]; Wih0T: [i=256][o=768]
// Wh: f16 [c=6][o=384][k=128]  (Whh row-major)
// Wx: f16 [cc=4][o=384][k=256] (Wih row-major, cells 2..5)
__global__ void k_prep(const float* __restrict__ WvP, const float* __restrict__ WvPb,
                       const float* __restrict__ gatew,
                       const float* __restrict__ Wih, const float* __restrict__ Whh,
                       float* __restrict__ WvPT, float* __restrict__ WvPbT,
                       float* __restrict__ gwT, float* __restrict__ Wih0T,
                       _Float16* __restrict__ Wx, _Float16* __restrict__ Wh) {
  int n = blockIdx.x*blockDim.x + threadIdx.x;
  int NT = gridDim.x*blockDim.x;
  for (int k = n; k < 256*128; k += NT) {
    int i = k >> 7, h = k & 127;
    WvPT[k]  = WvP[h*256 + i];
    WvPbT[k] = WvPb[h*256 + i];
  }
  for (int k = n; k < 256*256; k += NT) {
    int dd = k >> 8, e = k & 255;
    gwT[k] = gatew[e*256 + dd];
  }
  for (int k = n; k < 256*768; k += NT) {
    int i = k / 768, doo = k % 768;
    Wih0T[k] = Wih[(size_t)doo*256 + i];
  }
  for (int k = n; k < 6*384*128; k += NT) {
    Wh[k] = (_Float16)Whh[k];           // identical flat layout [c][o][128]
  }
  for (int k = n; k < 4*384*256; k += NT) {
    Wx[k] = (_Float16)Wih[(size_t)2*384*256 + k];  // cells 2..5 = Wih rows 2..5
  }
}

// ---------------- prep/pbar projections ----------------
__global__ __launch_bounds__(256) void k_prep_pbar(
    const float* __restrict__ P, const float* __restrict__ WvPT,
    const float* __restrict__ WvPbT, float* __restrict__ prepT,
    float* __restrict__ pbar) {
  __shared__ float Pl[4*256];
  int R0 = blockIdx.x * 4, tid = threadIdx.x;
  for (int k = tid; k < 1024; k += 256) Pl[k] = P[(size_t)R0*256 + k];
  __syncthreads();
  int h = tid & 127;
  const float* Wt = (tid < 128) ? WvPT : WvPbT;
  float acc[4] = {0,0,0,0};
  for (int i = 0; i < 256; ++i) {
    float w = Wt[i*128 + h];
    acc[0] += Pl[i]*w; acc[1] += Pl[256+i]*w;
    acc[2] += Pl[512+i]*w; acc[3] += Pl[768+i]*w;
  }
  #pragma unroll
  for (int r = 0; r < 4; ++r) {
    int R = R0 + r, t = R >> 3, b = R & 7;
    if (tid < 128) prepT[((size_t)b*128 + h)*256 + t] = acc[r];
    else           pbar[(size_t)R*128 + h] = acc[r];
  }
}

// ---------------- fused attention + gate ----------------
__global__ __launch_bounds__(256) void k_attn(
    const float* __restrict__ prepT, const float* __restrict__ pbar,
    const float* __restrict__ vw, const float* __restrict__ gwT,
    float* __restrict__ ug) {
  int b = blockIdx.x & 7, q0 = (blockIdx.x >> 3) * 4;
  int tid = threadIdx.x;
  __shared__ float u[4][256];
  __shared__ float vl[128];
  __shared__ float sc[4][256];
  __shared__ float red[4];
  if (tid < 128) vl[tid] = vw[tid];
  for (int k = tid; k < 512; k += 256) {
    int j = k >> 7, h = k & 127;
    u[j][h] = pbar[(((size_t)(q0+j))*8 + b)*128 + h];
  }
  __syncthreads();
  float s[4] = {0,0,0,0};
  for (int h = 0; h < 128; ++h) {
    float pk = prepT[((size_t)b*128 + h)*256 + tid];
    float vh = vl[h];
    #pragma unroll
    for (int j = 0; j < 4; ++j) {
      float e = __expf(2.f*(u[j][h] + pk));
      s[j] += vh * (1.f - 2.f/(e + 1.f));
    }
  }
  #pragma unroll
  for (int j = 0; j < 4; ++j) {
    float v = s[j];
    #pragma unroll
    for (int off = 32; off > 0; off >>= 1) v = fmaxf(v, __shfl_xor(v, off));
    if ((tid & 63) == 0) red[tid >> 6] = v;
    __syncthreads();
    float m = fmaxf(fmaxf(red[0], red[1]), fmaxf(red[2], red[3]));
    __syncthreads();
    float e = __expf(s[j] - m);
    v = e;
    #pragma unroll
    for (int off = 32; off > 0; off >>= 1) v += __shfl_xor(v, off);
    if ((tid & 63) == 0) red[tid >> 6] = v;
    __syncthreads();
    float sum = red[0] + red[1] + red[2] + red[3];
    __syncthreads();
    sc[j][tid] = e / sum;
  }
  __syncthreads();
  {
    int h = tid & 127, jj = tid >> 7;
    float c0 = 0.f, c1 = 0.f;
    for (int k = 0; k < 256; ++k) {
      float p = pbar[((size_t)k*8 + b)*128 + h];
      c0 += sc[jj][k]   * p;
      c1 += sc[jj+2][k] * p;
    }
    u[jj][128+h]   = c0;
    u[jj+2][128+h] = c1;
  }
  __syncthreads();
  {
    float gg[4] = {0,0,0,0};
    for (int dd = 0; dd < 256; ++dd) {
      float w = gwT[(size_t)dd*256 + tid];
      #pragma unroll
      for (int j = 0; j < 4; ++j) gg[j] += u[j][dd] * w;
    }
    #pragma unroll
    for (int j = 0; j < 4; ++j) {
      float ue = u[j][tid];
      ug[(((size_t)(q0+j))*8 + b)*256 + tid] = ue * fsig(gg[j]);
    }
  }
}

// ---------------- gi0 = ug @ Wih0^T + bih : output [t][o=768][b=8] ----------------
__global__ __launch_bounds__(256) void k_gi0(
    const float* __restrict__ ug, const float* __restrict__ Wih0T,
    const float* __restrict__ bih, float* __restrict__ gi0) {
  __shared__ float ul[8][256];
  __shared__ float st[768*8];
  int t = blockIdx.x, tid = threadIdx.x;
  for (int k = tid; k < 2048; k += 256) ul[k >> 8][k & 255] = ug[(size_t)t*2048 + k];
  __syncthreads();
  float acc[3][8];
  #pragma unroll
  for (int a = 0; a < 3; ++a)
    #pragma unroll
    for (int r = 0; r < 8; ++r) acc[a][r] = 0.f;
  for (int i = 0; i < 256; ++i) {
    float w0 = Wih0T[(size_t)i*768 + tid];
    float w1 = Wih0T[(size_t)i*768 + 256 + tid];
    float w2 = Wih0T[(size_t)i*768 + 512 + tid];
    #pragma unroll
    for (int r = 0; r < 8; ++r) {
      float uu = ul[r][i];
      acc[0][r] += uu*w0; acc[1][r] += uu*w1; acc[2][r] += uu*w2;
    }
  }
  float b0 = bih[tid], b1 = bih[256 + tid], b2 = bih[512 + tid];
  #pragma unroll
  for (int a = 0; a < 3; ++a) {
    int o = a*256 + tid;
    float ba = (a == 0) ? b0 : (a == 1) ? b1 : b2;
    #pragma unroll
    for (int r = 0; r < 8; ++r) st[o*8 + r] = acc[a][r] + ba;
  }
  __syncthreads();
  #pragma unroll
  for (int j = 0; j < 6; ++j) {
    int idx = j*256 + tid;
    ((f32x4*)gi0)[(size_t)t*1536 + idx] = ((const f32x4*)st)[idx];
  }
}

// ---------------- persistent GRU v5: chunked handoff + PINNED weights --------
// Identical skeleton to v4 (passed, absmax 2e-3). One change: weight B-frags
// are pinned as opaque asm register defs so the compiler cannot sink/remat the
// weight loads into the step loop (v4 showed VGPR_Count=124 < 144 weight regs
// -> per-step L2 restream on the MFMA critical path).
__global__ __launch_bounds__(512, 2) void k_gru5(
    const _Float16* __restrict__ Wx, const _Float16* __restrict__ Wh,
    const float* __restrict__ gi0, const float* __restrict__ bih,
    const float* __restrict__ bhh, unsigned long long* Hbuf,
    float* __restrict__ out, unsigned* flags)
{
  const int c = blockIdx.x, l = c >> 1, d = c & 1;
  const int tid = threadIdx.x;
  const int w = tid >> 6, lane = tid & 63;
  const int lo = lane & 15, hi = lane >> 4;

  __shared__ _Float16 XL[CHUNK * 8 * 256];   // 32 KiB: [tt][b(512B row)][256 f16], swizzled
  __shared__ _Float16 hlds[2][8*128];        // 4 KiB double-buffered own h

  { // zero both h buffers
    f16x8 z = {0,0,0,0,0,0,0,0};
    for (int p = tid; p < 256; p += 512) ((f16x8*)hlds)[p] = z;
  }

  // ---- B-fragments (weights) into registers, then PIN ----
  f16x8 bh[3][4];
  #pragma unroll
  for (int nt = 0; nt < 3; ++nt) {
    int o = 16 * (w + 8*nt) + lo;
    #pragma unroll
    for (int ks = 0; ks < 4; ++ks)
      bh[nt][ks] = *(const f16x8*)(Wh + ((size_t)c*384 + o)*128 + 32*ks + 8*hi);
  }
  #pragma unroll
  for (int nt = 0; nt < 3; ++nt)
    #pragma unroll
    for (int ks = 0; ks < 4; ++ks)
      PIN(bh[nt][ks]);

  f16x8 bx[3][8];
  if (l > 0) {
    #pragma unroll
    for (int nt = 0; nt < 3; ++nt) {
      int o = 16 * (w + 8*nt) + lo;
      #pragma unroll
      for (int ks = 0; ks < 8; ++ks)
        bx[nt][ks] = *(const f16x8*)(Wx + ((size_t)(c-2)*384 + o)*256 + 32*ks + 8*hi);
    }
    #pragma unroll
    for (int nt = 0; nt < 3; ++nt)
      #pragma unroll
      for (int ks = 0; ks < 8; ++ks)
        PIN(bx[nt][ks]);
  }

  // ---- per-lane biases (h index = 16w + lo; gates r,z,n) ----
  const int hidx = 16*w + lo;
  float b_r, b_z, b_in, b_hn;
  {
    const size_t bb = (size_t)c * 384;
    float bir = bih[bb + hidx], biz = bih[bb + 128 + hidx], bin = bih[bb + 256 + hidx];
    float bhr = bhh[bb + hidx], bhz = bhh[bb + 128 + hidx], bhn = bhh[bb + 256 + hidx];
    if (l == 0) { b_r = bhr; b_z = bhz; b_in = 0.f;  b_hn = bhn; }
    else        { b_r = bir + bhr; b_z = biz + bhz; b_in = bin; b_hn = bhn; }
  }

  const int cinf = (l - 1) * 2;

  f32x4 gx0, gx1, gx2;
  auto issue_g = [&](int t) {
    const float* g = gi0 + ((size_t)t*768 + (size_t)d*384) * 8;
    int b0 = 4 * (hi & 1);
    gx0 = *(const f32x4*)(g + (size_t)hidx*8 + b0);
    gx1 = *(const f32x4*)(g + ((size_t)128 + hidx)*8 + b0);
    gx2 = *(const f32x4*)(g + ((size_t)256 + hidx)*8 + b0);
  };

  float hp[4] = {0,0,0,0};
  if (l == 0) issue_g(0);
  __syncthreads();

  for (int tc = 0; tc < NCHUNK; ++tc) {
    // ---- chunk handoff: poll both producer flags, bulk-load x chunk ----
    if (l > 0) {
      if (tid == 0) {
        while (__hip_atomic_load(flags + cinf, __ATOMIC_RELAXED,
                                 __HIP_MEMORY_SCOPE_AGENT) <= (unsigned)tc)
          __builtin_amdgcn_s_sleep(8);
        while (__hip_atomic_load(flags + cinf + 1, __ATOMIC_RELAXED,
                                 __HIP_MEMORY_SCOPE_AGENT) <= (unsigned)tc)
          __builtin_amdgcn_s_sleep(8);
        __builtin_amdgcn_fence(__ATOMIC_ACQUIRE, "agent");
      }
      __syncthreads();   // also closes WAR on XL from previous chunk
      #pragma unroll
      for (int r = 0; r < 8; ++r) {
        int u = r*512 + tid;                  // 4096 8B units
        int cell = u >> 11, rem = u & 2047;
        int tt = rem >> 8, b = (rem >> 5) & 7, p = rem & 31;
        unsigned long long v = __hip_atomic_load(
            Hbuf + (((size_t)(cinf + cell)) << 16)
                 + (size_t)(tc*CHUNK + tt)*256 + b*32 + p,
            __ATOMIC_RELAXED, __HIP_MEMORY_SCOPE_AGENT);
        int byte = (tt*4096 + b*512 + cell*256 + p*8) ^ ((b & 7) << 4);
        *(unsigned long long*)((char*)XL + byte) = v;
      }
      __syncthreads();
    }

    // ---- 8 steps from LDS/registers ----
    for (int tt = 0; tt < CHUNK; ++tt) {
      const int t = tc*CHUNK + tt;
      // h-part MFMAs from hlds[t&1]
      f32x4 ah0 = {0,0,0,0}, ah1 = {0,0,0,0}, ah2 = {0,0,0,0};
      {
        const char* hb = (const char*)hlds[t & 1];
        f16x8 a[4];
        #pragma unroll
        for (int ks = 0; ks < 4; ++ks) {
          int byte = ((lo & 7)*256 + (32*ks + 8*hi)*2) ^ ((lo & 7) << 4);
          a[ks] = *(const f16x8*)(hb + byte);
        }
        #pragma unroll
        for (int ks = 0; ks < 4; ++ks) {
          ah0 = MFMA16(a[ks], bh[0][ks], ah0);
          ah1 = MFMA16(a[ks], bh[1][ks], ah1);
          ah2 = MFMA16(a[ks], bh[2][ks], ah2);
        }
      }
      // x-part
      f32x4 ax0, ax1, ax2;
      if (l > 0) {
        ax0 = (f32x4){0,0,0,0}; ax1 = (f32x4){0,0,0,0}; ax2 = (f32x4){0,0,0,0};
        f16x8 a[8];
        #pragma unroll
        for (int ks = 0; ks < 8; ++ks) {
          int byte = (tt*4096 + (lo & 7)*512 + 64*ks + 16*hi) ^ ((lo & 7) << 4);
          a[ks] = *(const f16x8*)((const char*)XL + byte);
        }
        #pragma unroll
        for (int ks = 0; ks < 8; ++ks) {
          ax0 = MFMA16(a[ks], bx[0][ks], ax0);
          ax1 = MFMA16(a[ks], bx[1][ks], ax1);
          ax2 = MFMA16(a[ks], bx[2][ks], ax2);
        }
      } else {
        ax0 = gx0; ax1 = gx1; ax2 = gx2;
        if (t < T_LEN - 1) issue_g(t + 1);
      }
      // combine gates + state update (lanes<32: b = 4*hi+q)
      float hn[4];
      #pragma unroll
      for (int q = 0; q < 4; ++q) {
        float r  = fsig(ax0[q] + ah0[q] + b_r);
        float z  = fsig(ax1[q] + ah1[q] + b_z);
        float nn = ftanhf(ax2[q] + b_in + r * (ah2[q] + b_hn));
        hn[q] = (1.f - z) * nn + z * hp[q];
        hp[q] = hn[q];
      }
      // write h(t) into hlds[(t+1)&1] + out (l==2)
      if (lane < 32) {
        char* hb2 = (char*)hlds[(t + 1) & 1];
        #pragma unroll
        for (int q = 0; q < 4; ++q) {
          int b = 4*hi + q;
          int byte = (b*256 + hidx*2) ^ (b << 4);
          *(_Float16*)(hb2 + byte) = (_Float16)hn[q];
          if (l == 2) out[((size_t)b*256 + t)*256 + d*128 + hidx] = hn[q];
        }
      }
      __syncthreads();
      // publish h(t): fire-and-forget agent atomics (producers l<2)
      if (l < 2 && tid < 128) {
        int b = tid >> 4, p = tid & 15;
        int byte = (b*256 + p*16) ^ (b << 4);
        const unsigned long long* src =
            (const unsigned long long*)((const char*)hlds[(t + 1) & 1] + byte);
        unsigned long long v0 = src[0], v1 = src[1];
        size_t idx = (((size_t)c) << 16) + (size_t)t*256 + (size_t)b*32 + 2*p;
        __hip_atomic_store(Hbuf+idx,   v0, __ATOMIC_RELAXED, __HIP_MEMORY_SCOPE_AGENT);
        __hip_atomic_store(Hbuf+idx+1, v1, __ATOMIC_RELAXED, __HIP_MEMORY_SCOPE_AGENT);
      }
    }

    // ---- raise chunk flag (producers) ----
    if (l < 2) {
      asm volatile("s_waitcnt vmcnt(0)" ::: "memory");  // drain this thread's stores
      __syncthreads();                                  // all threads drained
      if (tid == 0)
        __hip_atomic_store(flags + c, (unsigned)(tc + 1),
                           __ATOMIC_RELEASE, __HIP_MEMORY_SCOPE_AGENT);
    }
  }
}

extern "C" void kernel_launch(void* const* d_in, const int* in_sizes, int n_in,
                              void* d_out, int out_size, void* d_ws, size_t ws_size,
                              hipStream_t stream) {
  (void)in_sizes; (void)n_in; (void)out_size; (void)ws_size;
  const float* P     = (const float*)d_in[0];
  const float* vw    = (const float*)d_in[2];
  const float* WvP   = (const float*)d_in[3];
  const float* WvPb  = (const float*)d_in[4];
  const float* gatew = (const float*)d_in[5];
  const float* Wih   = (const float*)d_in[6];
  const float* Whh   = (const float*)d_in[7];
  const float* bih   = (const float*)d_in[8];
  const float* bhh   = (const float*)d_in[9];
  float* out = (float*)d_out;

  char* wsp = (char*)d_ws;
  size_t off = 0;
  auto alloc = [&](size_t nbytes) -> void* {
    void* p = wsp + off;
    off += (nbytes + 255) & ~(size_t)255;
    return p;
  };
  float*    prepT = (float*)   alloc((size_t)8*128*256*4);
  float*    pbar  = (float*)   alloc((size_t)256*8*128*4);
  float*    ug    = (float*)   alloc((size_t)256*8*256*4);
  float*    gi0   = (float*)   alloc((size_t)256*768*8*4);     // [t][o][b]
  unsigned long long* Hbuf = (unsigned long long*)alloc((size_t)4*256*8*32*8);
  _Float16* Wx    = (_Float16*)alloc((size_t)4*384*256*2);
  _Float16* Wh    = (_Float16*)alloc((size_t)6*384*128*2);
  float*    WvPT  = (float*)   alloc((size_t)256*128*4);
  float*    WvPbT = (float*)   alloc((size_t)256*128*4);
  float*    gwT   = (float*)   alloc((size_t)256*256*4);
  float*    Wih0T = (float*)   alloc((size_t)256*768*4);
  unsigned* flags = (unsigned*)alloc((size_t)64*4);

  hipLaunchKernelGGL(k_init, dim3(1), dim3(64), 0, stream, flags);
  hipLaunchKernelGGL(k_prep, dim3(256), dim3(256), 0, stream,
                     WvP, WvPb, gatew, Wih, Whh, WvPT, WvPbT, gwT, Wih0T, Wx, Wh);
  hipLaunchKernelGGL(k_prep_pbar, dim3(512), dim3(256), 0, stream,
                     P, WvPT, WvPbT, prepT, pbar);
  hipLaunchKernelGGL(k_attn, dim3(512), dim3(256), 0, stream,
                     prepT, pbar, vw, gwT, ug);
  hipLaunchKernelGGL(k_gi0, dim3(256), dim3(256), 0, stream,
                     ug, Wih0T, bih, gi0);
  hipLaunchKernelGGL(k_gru5, dim3(6), dim3(512), 0, stream,
                     Wx, Wh, gi0, bih, bhh, Hbuf, out, flags);
}